// Round 1
// baseline (46.741 us; speedup 1.0000x reference)
//
#include <hip/hip_runtime.h>

// YOLO loss: out,label [32768,17,7,7] f32 -> scalar f32.
// Per-batch stride = 17*49 = 833 floats; mask = label channel0 (exactly 0/1).
// Per-channel weights with per-cell mask s:
//   c==0 : d0^2 * (s ? 1 : 0.5)
//   c in {1,2}: 5*s*(l-o)^2
//   c in {3,4}: 5*s*(sqrt(l)-sqrt(o))^2
//   c in 5..16: s*(l-o)^2
// Sum / (B*49).

#define BPC   833
#define CELLS 49
#define NTOT  (32768 * BPC)   // 27,295,744 floats per tensor
#define N4    (NTOT / 4)      // 6,823,936 float4s (divisible: B even)
#define NBLK  2048

__global__ __launch_bounds__(256) void yolo_partial(const float* __restrict__ outp,
                                                    const float* __restrict__ lab,
                                                    float* __restrict__ partial) {
    const int tid    = blockIdx.x * 256 + threadIdx.x;
    const int stride = gridDim.x * 256;
    float acc = 0.0f;

    for (int i4 = tid; i4 < N4; i4 += stride) {
        const float4 o4 = reinterpret_cast<const float4*>(outp)[i4];
        const float4 l4 = reinterpret_cast<const float4*>(lab)[i4];
        const float ov[4] = {o4.x, o4.y, o4.z, o4.w};
        const float lv[4] = {l4.x, l4.y, l4.z, l4.w};
        const int base = i4 * 4;
#pragma unroll
        for (int j = 0; j < 4; ++j) {
            const int idx  = base + j;
            const int b    = idx / BPC;          // magic-mul (const divisor)
            const int r    = idx - b * BPC;
            const int c    = r / CELLS;
            const int cell = r - c * CELLS;
            const float o1 = ov[j];
            const float l1 = lv[j];
            float contrib;
            if (c == 0) {
                const float d = l1 - o1;
                contrib = d * d * ((l1 != 0.0f) ? 1.0f : 0.5f);
            } else {
                const float m = lab[b * BPC + cell];   // L1/L2-hot (49 floats/batch)
                const float s = (m != 0.0f) ? 1.0f : 0.0f;
                float d, w;
                if (c >= 5)      { d = l1 - o1;                     w = s;        }
                else if (c >= 3) { d = sqrtf(l1) - sqrtf(o1);       w = 5.0f * s; }
                else             { d = l1 - o1;                     w = 5.0f * s; }
                contrib = w * d * d;
            }
            acc += contrib;
        }
    }

    // wave64 shuffle reduce
#pragma unroll
    for (int off = 32; off > 0; off >>= 1)
        acc += __shfl_down(acc, off, 64);

    __shared__ float wsum[4];
    const int lane = threadIdx.x & 63;
    const int wid  = threadIdx.x >> 6;
    if (lane == 0) wsum[wid] = acc;
    __syncthreads();
    if (threadIdx.x == 0)
        partial[blockIdx.x] = wsum[0] + wsum[1] + wsum[2] + wsum[3];
}

__global__ __launch_bounds__(256) void yolo_final(const float* __restrict__ partial,
                                                  float* __restrict__ outv) {
    float acc = 0.0f;
    for (int i = threadIdx.x; i < NBLK; i += 256) acc += partial[i];
#pragma unroll
    for (int off = 32; off > 0; off >>= 1)
        acc += __shfl_down(acc, off, 64);

    __shared__ float wsum[4];
    const int lane = threadIdx.x & 63;
    const int wid  = threadIdx.x >> 6;
    if (lane == 0) wsum[wid] = acc;
    __syncthreads();
    if (threadIdx.x == 0)
        outv[0] = (wsum[0] + wsum[1] + wsum[2] + wsum[3]) * (1.0f / 1605632.0f);
}

extern "C" void kernel_launch(void* const* d_in, const int* in_sizes, int n_in,
                              void* d_out, int out_size, void* d_ws, size_t ws_size,
                              hipStream_t stream) {
    const float* outp = (const float*)d_in[0];
    const float* lab  = (const float*)d_in[1];
    float* partial    = (float*)d_ws;          // NBLK floats (8 KB)
    float* res        = (float*)d_out;

    yolo_partial<<<NBLK, 256, 0, stream>>>(outp, lab, partial);
    yolo_final<<<1, 256, 0, stream>>>(partial, res);
}